// Round 16
// baseline (81.101 us; speedup 1.0000x reference)
//
#include <hip/hip_runtime.h>

using bf16x8 = __attribute__((ext_vector_type(8))) short;
using u16x8  = __attribute__((ext_vector_type(8))) unsigned short;
using u32x4  = __attribute__((ext_vector_type(4))) unsigned;
using f32x4  = __attribute__((ext_vector_type(4))) float;

static constexpr int S  = 2048;
static constexpr int D  = 64;
static constexpr int TQ = 64;
static constexpr float QSCALE = 0.18033688f; // log2(e)/8 : exp2(dot) == exp(dot/8)

// HW packed f32->bf16 convert, RNE (v_cvt_pk_bf16_f32)
__device__ __forceinline__ unsigned cvtpk(float lo, float hi) {
    unsigned r;
    asm("v_cvt_pk_bf16_f32 %0, %1, %2" : "=v"(r) : "v"(lo), "v"(hi));
    return r;
}
__device__ __forceinline__ f32x4 mfma16(bf16x8 a, bf16x8 b, f32x4 c) {
    return __builtin_amdgcn_mfma_f32_16x16x32_bf16(a, b, c, 0, 0, 0);
}
// LDS-visibility barrier only: does NOT drain vmcnt (stores stay in flight)
__device__ __forceinline__ void lbar() {
    asm volatile("s_waitcnt lgkmcnt(0)" ::: "memory");
    __builtin_amdgcn_s_barrier();
    asm volatile("" ::: "memory");
}

// Block = ONE (batch, qt) 64-row strip; 256 threads / 4 decoupled waves; grid=512
// -> 2 blocks/CU. Dispatch: early half big-qt desc, late half small-qt asc ->
// co-resident pairs anti-correlated in work. Wave wv owns 16-row K chunks
// c ≡ wv (mod 4), staged to a private double-buffered LDS slot, depth-2 even/odd
// register prefetch. Q single-bf16 (QSCALE folded). MFMA swapped (A=K, B=Q).
// ZERO-FILL IS HOISTED TO KERNEL START: its stores fire-and-forget and drain
// under pass A's (store-free) compute — lbar never waits vmcnt, so nothing
// forces a drain until end-of-kernel.
__global__ __launch_bounds__(256, 2)
void monotonic_attn(const float* __restrict__ Qg, const float* __restrict__ Kg,
                    float* __restrict__ out)
{
    __shared__ unsigned short qlds[4096];        // Q bf16 (scaled), XOR-swizzled
    __shared__ unsigned short kls[4][2][1024];   // per-wave dbuf: 16 rows x 64 bf16
    __shared__ float red[4][64];

    const int bid  = blockIdx.x;
    const int xcd  = bid & 7;
    const int m    = bid >> 3;                   // 0..63 dispatch order within XCD
    const int bloc = (m < 32) ? 0 : 1;
    const int qt   = (m < 32) ? (31 - m) : (m - 32);
    const int b    = 2 * xcd + bloc;

    const int tid = threadIdx.x, lane = tid & 63, wv = tid >> 6;  // wv 0..3
    const int l15 = lane & 15, g = lane >> 4;

    const float* __restrict__ Qb = Qg + (size_t)b * S * D;
    const float* __restrict__ Kb = Kg + (size_t)b * S * D;
    float* __restrict__ outb = out + (size_t)b * (size_t)S * S;

    const int q0   = qt * TQ;
    const int kend = q0 + TQ;
    const int nC   = kend >> 4;                  // 16-row K chunks in [0,kend)
    const int ni   = (nC - wv + 3) >> 2;         // this wave's chunk count (>=1)

    // ---------------- zero-fill cols >= kend FIRST (stores drain under pass A) ----------------
    {
        f32x4 z = {0.f, 0.f, 0.f, 0.f};
        const size_t rb = (size_t)(q0 + (tid >> 2)) * S;
        for (int cc = kend + (tid & 3) * 4; cc < S; cc += 16)
            *reinterpret_cast<f32x4*>(&outb[rb + cc]) = z;
    }

    // K staging geometry (per wave): lane covers 16 floats of the 1024-float chunk
    const int srow  = lane >> 2;                 // row 0..15 within chunk
    const int scp   = lane & 3;                  // 16-float group -> 2 8-short chunks
    const int woff0 = srow * 64 + (((scp << 1)    ) ^ (srow & 7)) * 8;
    const int woff1 = srow * 64 + (((scp << 1) | 1) ^ (srow & 7)) * 8;
    const int roff0 = l15 * 64 + ((g    ) ^ (l15 & 7)) * 8;    // d-cols [8g,8g+8)
    const int roff1 = l15 * 64 + ((4 | g) ^ (l15 & 7)) * 8;    // d-cols [32+8g,+8)

    // ---------------- stage Q (scaled, bf16 via cvt_pk, XOR-swizzled) ----------------
    {
        const int qrow = tid >> 2, qc = tid & 3;
        const float4* src = reinterpret_cast<const float4*>(Qb + (size_t)(q0 + qrow) * D + qc * 16);
        float v[16];
        *reinterpret_cast<float4*>(&v[0])  = src[0];
        *reinterpret_cast<float4*>(&v[4])  = src[1];
        *reinterpret_cast<float4*>(&v[8])  = src[2];
        *reinterpret_cast<float4*>(&v[12]) = src[3];
        #pragma unroll
        for (int j = 0; j < 2; ++j) {
            u32x4 w;
            #pragma unroll
            for (int p = 0; p < 4; ++p)
                w[p] = cvtpk(v[8 * j + 2 * p] * QSCALE, v[8 * j + 2 * p + 1] * QSCALE);
            const int chunk = qc * 2 + j;
            const int off = qrow * 64 + (chunk ^ (qrow & 7)) * 8;
            *reinterpret_cast<u32x4*>(&qlds[off]) = w;
        }
    }
    lbar();                                      // Q staged before frag reads

    bf16x8 qf[4][2];
    #pragma unroll
    for (int qs = 0; qs < 4; ++qs) {
        const int row = qs * 16 + l15;
        #pragma unroll
        for (int c = 0; c < 2; ++c) {
            const int off = row * 64 + ((((c << 2) | g)) ^ (row & 7)) * 8;
            qf[qs][c] = *reinterpret_cast<const bf16x8*>(&qlds[off]);
        }
    }

    float inv4[4];
    for (int pass = 0; pass < 2; ++pass) {
        float rsum[4] = {0.f, 0.f, 0.f, 0.f};

        float4 ra0, ra1, ra2, ra3, rb0, rb1, rb2, rb3;   // two named reg sets
        auto issueA = [&](int i) {
            const float4* p4 = reinterpret_cast<const float4*>(Kb) + ((wv + 4 * i) << 8) + (lane << 2);
            ra0 = p4[0]; ra1 = p4[1]; ra2 = p4[2]; ra3 = p4[3];
        };
        auto issueB = [&](int i) {
            const float4* p4 = reinterpret_cast<const float4*>(Kb) + ((wv + 4 * i) << 8) + (lane << 2);
            rb0 = p4[0]; rb1 = p4[1]; rb2 = p4[2]; rb3 = p4[3];
        };
        auto stage = [&](int i, const float4& x0, const float4& x1,
                         const float4& x2, const float4& x3) {
            u32x4 w0, w1;
            w0[0] = cvtpk(x0.x, x0.y); w0[1] = cvtpk(x0.z, x0.w);
            w0[2] = cvtpk(x1.x, x1.y); w0[3] = cvtpk(x1.z, x1.w);
            w1[0] = cvtpk(x2.x, x2.y); w1[1] = cvtpk(x2.z, x2.w);
            w1[2] = cvtpk(x3.x, x3.y); w1[3] = cvtpk(x3.z, x3.w);
            unsigned short* bp = &kls[wv][i & 1][0];
            *reinterpret_cast<u32x4*>(&bp[woff0]) = w0;
            *reinterpret_cast<u32x4*>(&bp[woff1]) = w1;
        };
        auto comp = [&](int i) {
            const unsigned short* bp = &kls[wv][i & 1][0];
            const bf16x8 kf0 = *reinterpret_cast<const bf16x8*>(&bp[roff0]);
            const bf16x8 kf1 = *reinterpret_cast<const bf16x8*>(&bp[roff1]);
            const int klo = (wv + 4 * i) << 4;
            const int kb  = klo + g * 4;
            #pragma unroll
            for (int qs = 0; qs < 4; ++qs) {
                const int qmin = q0 + qs * 16, qg = qmin + l15;
                if (pass == 0) {
                    if (klo > qmin + 15) continue;
                    f32x4 acc = {0.f, 0.f, 0.f, 0.f};
                    acc = mfma16(kf0, qf[qs][0], acc);
                    acc = mfma16(kf1, qf[qs][1], acc);
                    if (klo + 15 <= qmin) {
                        rsum[qs] += exp2f(acc[0]) + exp2f(acc[1]) + exp2f(acc[2]) + exp2f(acc[3]);
                    } else {
                        #pragma unroll
                        for (int r = 0; r < 4; ++r)
                            rsum[qs] += (kb + r <= qg) ? exp2f(acc[r]) : 0.f;
                    }
                } else {
                    f32x4 ov = {0.f, 0.f, 0.f, 0.f};
                    if (klo <= qmin + 15) {
                        f32x4 acc = {0.f, 0.f, 0.f, 0.f};
                        acc = mfma16(kf0, qf[qs][0], acc);
                        acc = mfma16(kf1, qf[qs][1], acc);
                        if (klo + 15 <= qmin) {
                            ov[0] = exp2f(acc[0]) * inv4[qs];
                            ov[1] = exp2f(acc[1]) * inv4[qs];
                            ov[2] = exp2f(acc[2]) * inv4[qs];
                            ov[3] = exp2f(acc[3]) * inv4[qs];
                        } else {
                            ov[0] = (kb + 0 <= qg) ? exp2f(acc[0]) * inv4[qs] : 0.f;
                            ov[1] = (kb + 1 <= qg) ? exp2f(acc[1]) * inv4[qs] : 0.f;
                            ov[2] = (kb + 2 <= qg) ? exp2f(acc[2]) * inv4[qs] : 0.f;
                            ov[3] = (kb + 3 <= qg) ? exp2f(acc[3]) * inv4[qs] : 0.f;
                        }
                    }
                    *reinterpret_cast<f32x4*>(outb + (size_t)qg * S + kb) = ov;
                }
            }
        };

        // per-wave pipeline, depth-2 prefetch, even/odd unrolled (static reg sets)
        if (ni > 0) issueA(0);
        if (ni > 1) issueB(1);
        int i = 0;
        for (; i + 2 <= ni; i += 2) {
            stage(i, ra0, ra1, ra2, ra3);
            if (i + 2 < ni) issueA(i + 2);
            comp(i);
            stage(i + 1, rb0, rb1, rb2, rb3);
            if (i + 3 < ni) issueB(i + 3);
            comp(i + 1);
        }
        if (i < ni) { stage(i, ra0, ra1, ra2, ra3); comp(i); }

        if (pass == 0) {                         // cross-wave row-sum reduction
            #pragma unroll
            for (int qs = 0; qs < 4; ++qs) {
                float v = rsum[qs];
                v += __shfl_xor(v, 16);
                v += __shfl_xor(v, 32);
                if (g == 0) red[wv][qs * 16 + l15] = v;
            }
            lbar();                              // sums visible
            #pragma unroll
            for (int qs = 0; qs < 4; ++qs) {
                const int qi = qs * 16 + l15;
                inv4[qs] = 1.f / (red[0][qi] + red[1][qi] + red[2][qi] + red[3][qi]);
            }
        }
    }
}

extern "C" void kernel_launch(void* const* d_in, const int* in_sizes, int n_in,
                              void* d_out, int out_size, void* d_ws, size_t ws_size,
                              hipStream_t stream)
{
    const float* Q = (const float*)d_in[0];
    const float* K = (const float*)d_in[1];
    float* out     = (float*)d_out;
    const int nb   = in_sizes[0] / (S * D);   // 16 batches

    monotonic_attn<<<dim3(nb * 32), dim3(256), 0, stream>>>(Q, K, out);
}

// Round 18
// 60.820 us; speedup vs baseline: 1.3335x; 1.3335x over previous
//
#include <hip/hip_runtime.h>

using bf16x8 = __attribute__((ext_vector_type(8))) short;
using u16x8  = __attribute__((ext_vector_type(8))) unsigned short;
using u32x4  = __attribute__((ext_vector_type(4))) unsigned;
using f32x4  = __attribute__((ext_vector_type(4))) float;

static constexpr int S  = 2048;
static constexpr int D  = 64;
static constexpr int TQ = 64;
static constexpr float QSCALE = 0.18033688f; // log2(e)/8 : exp2(dot) == exp(dot/8)

// HW packed f32->bf16 convert, RNE (v_cvt_pk_bf16_f32)
__device__ __forceinline__ unsigned cvtpk(float lo, float hi) {
    unsigned r;
    asm("v_cvt_pk_bf16_f32 %0, %1, %2" : "=v"(r) : "v"(lo), "v"(hi));
    return r;
}
__device__ __forceinline__ f32x4 mfma16(bf16x8 a, bf16x8 b, f32x4 c) {
    return __builtin_amdgcn_mfma_f32_16x16x32_bf16(a, b, c, 0, 0, 0);
}
// LDS-visibility barrier only: does NOT drain vmcnt
__device__ __forceinline__ void lbar() {
    asm volatile("s_waitcnt lgkmcnt(0)" ::: "memory");
    __builtin_amdgcn_s_barrier();
    asm volatile("" ::: "memory");
}

// Block = ONE (batch, qt) 64-row strip; 256 threads / 4 decoupled waves; grid=512
// -> 2 blocks/CU. Dispatch: early half big-qt desc, late half small-qt asc ->
// co-resident pairs anti-correlated in work. Wave wv owns 16-row K chunks
// c ≡ wv (mod 4), staged to a private double-buffered LDS slot, depth-2 even/odd
// register prefetch. Q single-bf16 (QSCALE folded). MFMA swapped (A=K, B=Q):
// lane's f32x4 = 4 consecutive k of one q row. bf16 conversion via HW cvt_pk (RNE).
__global__ __launch_bounds__(256, 2)
void monotonic_attn(const float* __restrict__ Qg, const float* __restrict__ Kg,
                    float* __restrict__ out)
{
    __shared__ unsigned short qlds[4096];        // Q bf16 (scaled), XOR-swizzled
    __shared__ unsigned short kls[4][2][1024];   // per-wave dbuf: 16 rows x 64 bf16
    __shared__ float red[4][64];

    const int bid  = blockIdx.x;
    const int xcd  = bid & 7;
    const int m    = bid >> 3;                   // 0..63 dispatch order within XCD
    const int bloc = (m < 32) ? 0 : 1;
    const int qt   = (m < 32) ? (31 - m) : (m - 32);
    const int b    = 2 * xcd + bloc;

    const int tid = threadIdx.x, lane = tid & 63, wv = tid >> 6;  // wv 0..3
    const int l15 = lane & 15, g = lane >> 4;

    const float* __restrict__ Qb = Qg + (size_t)b * S * D;
    const float* __restrict__ Kb = Kg + (size_t)b * S * D;
    float* __restrict__ outb = out + (size_t)b * (size_t)S * S;

    const int q0   = qt * TQ;
    const int kend = q0 + TQ;
    const int nC   = kend >> 4;                  // 16-row K chunks in [0,kend)
    const int ni   = (nC - wv + 3) >> 2;         // this wave's chunk count (>=1)

    // K staging geometry (per wave): lane covers 16 floats of the 1024-float chunk
    const int srow  = lane >> 2;                 // row 0..15 within chunk
    const int scp   = lane & 3;                  // 16-float group -> 2 8-short chunks
    const int woff0 = srow * 64 + (((scp << 1)    ) ^ (srow & 7)) * 8;
    const int woff1 = srow * 64 + (((scp << 1) | 1) ^ (srow & 7)) * 8;
    const int roff0 = l15 * 64 + ((g    ) ^ (l15 & 7)) * 8;    // d-cols [8g,8g+8)
    const int roff1 = l15 * 64 + ((4 | g) ^ (l15 & 7)) * 8;    // d-cols [32+8g,+8)

    // ---------------- stage Q (scaled, bf16 via cvt_pk, XOR-swizzled) ----------------
    {
        const int qrow = tid >> 2, qc = tid & 3;
        const float4* src = reinterpret_cast<const float4*>(Qb + (size_t)(q0 + qrow) * D + qc * 16);
        float v[16];
        *reinterpret_cast<float4*>(&v[0])  = src[0];
        *reinterpret_cast<float4*>(&v[4])  = src[1];
        *reinterpret_cast<float4*>(&v[8])  = src[2];
        *reinterpret_cast<float4*>(&v[12]) = src[3];
        #pragma unroll
        for (int j = 0; j < 2; ++j) {
            u32x4 w;
            #pragma unroll
            for (int p = 0; p < 4; ++p)
                w[p] = cvtpk(v[8 * j + 2 * p] * QSCALE, v[8 * j + 2 * p + 1] * QSCALE);
            const int chunk = qc * 2 + j;
            const int off = qrow * 64 + (chunk ^ (qrow & 7)) * 8;
            *reinterpret_cast<u32x4*>(&qlds[off]) = w;
        }
    }
    lbar();                                      // Q staged before frag reads

    bf16x8 qf[4][2];
    #pragma unroll
    for (int qs = 0; qs < 4; ++qs) {
        const int row = qs * 16 + l15;
        #pragma unroll
        for (int c = 0; c < 2; ++c) {
            const int off = row * 64 + ((((c << 2) | g)) ^ (row & 7)) * 8;
            qf[qs][c] = *reinterpret_cast<const bf16x8*>(&qlds[off]);
        }
    }

    float inv4[4];
    for (int pass = 0; pass < 2; ++pass) {
        float rsum[4] = {0.f, 0.f, 0.f, 0.f};

        float4 ra0, ra1, ra2, ra3, rb0, rb1, rb2, rb3;   // two named reg sets
        auto issueA = [&](int i) {
            const float4* p4 = reinterpret_cast<const float4*>(Kb) + ((wv + 4 * i) << 8) + (lane << 2);
            ra0 = p4[0]; ra1 = p4[1]; ra2 = p4[2]; ra3 = p4[3];
        };
        auto issueB = [&](int i) {
            const float4* p4 = reinterpret_cast<const float4*>(Kb) + ((wv + 4 * i) << 8) + (lane << 2);
            rb0 = p4[0]; rb1 = p4[1]; rb2 = p4[2]; rb3 = p4[3];
        };
        auto stage = [&](int i, const float4& x0, const float4& x1,
                         const float4& x2, const float4& x3) {
            u32x4 w0, w1;
            w0[0] = cvtpk(x0.x, x0.y); w0[1] = cvtpk(x0.z, x0.w);
            w0[2] = cvtpk(x1.x, x1.y); w0[3] = cvtpk(x1.z, x1.w);
            w1[0] = cvtpk(x2.x, x2.y); w1[1] = cvtpk(x2.z, x2.w);
            w1[2] = cvtpk(x3.x, x3.y); w1[3] = cvtpk(x3.z, x3.w);
            unsigned short* bp = &kls[wv][i & 1][0];
            *reinterpret_cast<u32x4*>(&bp[woff0]) = w0;
            *reinterpret_cast<u32x4*>(&bp[woff1]) = w1;
        };
        auto comp = [&](int i) {
            const unsigned short* bp = &kls[wv][i & 1][0];
            const bf16x8 kf0 = *reinterpret_cast<const bf16x8*>(&bp[roff0]);
            const bf16x8 kf1 = *reinterpret_cast<const bf16x8*>(&bp[roff1]);
            const int klo = (wv + 4 * i) << 4;
            const int kb  = klo + g * 4;
            #pragma unroll
            for (int qs = 0; qs < 4; ++qs) {
                const int qmin = q0 + qs * 16, qg = qmin + l15;
                if (pass == 0) {
                    if (klo > qmin + 15) continue;
                    f32x4 acc = {0.f, 0.f, 0.f, 0.f};
                    acc = mfma16(kf0, qf[qs][0], acc);
                    acc = mfma16(kf1, qf[qs][1], acc);
                    if (klo + 15 <= qmin) {
                        rsum[qs] += exp2f(acc[0]) + exp2f(acc[1]) + exp2f(acc[2]) + exp2f(acc[3]);
                    } else {
                        #pragma unroll
                        for (int r = 0; r < 4; ++r)
                            rsum[qs] += (kb + r <= qg) ? exp2f(acc[r]) : 0.f;
                    }
                } else {
                    f32x4 ov = {0.f, 0.f, 0.f, 0.f};
                    if (klo <= qmin + 15) {
                        f32x4 acc = {0.f, 0.f, 0.f, 0.f};
                        acc = mfma16(kf0, qf[qs][0], acc);
                        acc = mfma16(kf1, qf[qs][1], acc);
                        if (klo + 15 <= qmin) {
                            ov[0] = exp2f(acc[0]) * inv4[qs];
                            ov[1] = exp2f(acc[1]) * inv4[qs];
                            ov[2] = exp2f(acc[2]) * inv4[qs];
                            ov[3] = exp2f(acc[3]) * inv4[qs];
                        } else {
                            ov[0] = (kb + 0 <= qg) ? exp2f(acc[0]) * inv4[qs] : 0.f;
                            ov[1] = (kb + 1 <= qg) ? exp2f(acc[1]) * inv4[qs] : 0.f;
                            ov[2] = (kb + 2 <= qg) ? exp2f(acc[2]) * inv4[qs] : 0.f;
                            ov[3] = (kb + 3 <= qg) ? exp2f(acc[3]) * inv4[qs] : 0.f;
                        }
                    }
                    *reinterpret_cast<f32x4*>(outb + (size_t)qg * S + kb) = ov;
                }
            }
        };

        // per-wave pipeline, depth-2 prefetch, even/odd unrolled (static reg sets)
        if (ni > 0) issueA(0);
        if (ni > 1) issueB(1);
        int i = 0;
        for (; i + 2 <= ni; i += 2) {
            stage(i, ra0, ra1, ra2, ra3);
            if (i + 2 < ni) issueA(i + 2);
            comp(i);
            stage(i + 1, rb0, rb1, rb2, rb3);
            if (i + 3 < ni) issueB(i + 3);
            comp(i + 1);
        }
        if (i < ni) { stage(i, ra0, ra1, ra2, ra3); comp(i); }

        if (pass == 0) {                         // cross-wave row-sum reduction
            #pragma unroll
            for (int qs = 0; qs < 4; ++qs) {
                float v = rsum[qs];
                v += __shfl_xor(v, 16);
                v += __shfl_xor(v, 32);
                if (g == 0) red[wv][qs * 16 + l15] = v;
            }
            lbar();                              // sums visible
            #pragma unroll
            for (int qs = 0; qs < 4; ++qs) {
                const int qi = qs * 16 + l15;
                inv4[qs] = 1.f / (red[0][qi] + red[1][qi] + red[2][qi] + red[3][qi]);
            }
        }
    }

    // ---------------- zero-fill columns >= kend ----------------
    {
        f32x4 z = {0.f, 0.f, 0.f, 0.f};
        const size_t rb = (size_t)(q0 + (tid >> 2)) * S;
        for (int cc = kend + (tid & 3) * 4; cc < S; cc += 16)
            *reinterpret_cast<f32x4*>(&outb[rb + cc]) = z;
    }
}

extern "C" void kernel_launch(void* const* d_in, const int* in_sizes, int n_in,
                              void* d_out, int out_size, void* d_ws, size_t ws_size,
                              hipStream_t stream)
{
    const float* Q = (const float*)d_in[0];
    const float* K = (const float*)d_in[1];
    float* out     = (float*)d_out;
    const int nb   = in_sizes[0] / (S * D);   // 16 batches

    monotonic_attn<<<dim3(nb * 32), dim3(256), 0, stream>>>(Q, K, out);
}